// Round 4
// baseline (533.700 us; speedup 1.0000x reference)
//
#include <hip/hip_runtime.h>
#include <hip/hip_bf16.h>
#include <hip/hip_fp16.h>

typedef float f32x4 __attribute__((ext_vector_type(4)));
typedef float f32x2 __attribute__((ext_vector_type(2)));
typedef __bf16 bf16x8 __attribute__((ext_vector_type(8)));
typedef short s16x8 __attribute__((ext_vector_type(8)));
typedef unsigned short u16;
typedef unsigned short ushort4v __attribute__((ext_vector_type(4)));

#define HWSZ 16384
#define NPIX 131072

// ws byte offsets (total ~43.1 MB)
#define XT_OFF    0u          // float[NPIX*64]  x transposed to NHWC
#define OFFS_OFF  33554432u   // float[NPIX*18]  offset-conv output, [pix][18]
#define WB_OFF    42991616u   // u16[64*576]     deform_w as bf16, [o][k2*64+c]
#define OFFR_OFF  43065344u   // float[576*18]   offset_w reordered [k2*64+c][18]
#define STATS_OFF 43106816u   // float[256]: sums[64], sumsq[64], scale[64], shift[64]

__device__ inline float dpp_add_x1(float v) {   // v + shfl_xor(v,1) via quad_perm [1,0,3,2]
  int x = __builtin_amdgcn_update_dpp(0, __builtin_bit_cast(int, v), 0xB1, 0xF, 0xF, true);
  return v + __builtin_bit_cast(float, x);
}
__device__ inline float dpp_add_x2(float v) {   // v + shfl_xor(v,2) via quad_perm [2,3,0,1]
  int x = __builtin_amdgcn_update_dpp(0, __builtin_bit_cast(int, v), 0x4E, 0xF, 0xF, true);
  return v + __builtin_bit_cast(float, x);
}

// ---- prep: reorder/convert weights, zero BN stats ----
__global__ void kprep(const float* __restrict__ dw, const float* __restrict__ ow,
                      u16* __restrict__ Wb, float* __restrict__ offr,
                      float* __restrict__ stats) {
  int t = blockIdx.x * 256 + threadIdx.x;
  if (t < 256) stats[t] = 0.f;
  if (t < 36864) {                      // deform_w (64,64,3,3) -> Wb[o][k2*64+c] bf16
    int o = t / 576, r = t % 576;
    int c = r / 9, k2 = r % 9;
    __hip_bfloat16 h = __float2bfloat16(dw[t]);
    Wb[o * 576 + k2 * 64 + c] = __builtin_bit_cast(u16, h);
  } else if (t < 47232) {               // offset_w (18,64,3,3) -> offr[k2*64+c][18]
    int t2 = t - 36864;
    int oc = t2 / 576, r = t2 % 576;
    int c = r / 9, k2 = r % 9;
    offr[(k2 * 64 + c) * 18 + oc] = ow[t2];
  }
}

// ---- NCHW -> NHWC transpose of x ----
__global__ void ktrans(const float* __restrict__ x, float* __restrict__ xt) {
  __shared__ float tile[64][65];
  int blk = blockIdx.x;
  int b = blk >> 8, hwT = (blk & 255) * 64;
  int tx = threadIdx.x & 63, ty = threadIdx.x >> 6;
  const float* xp = x + (size_t)b * 64 * HWSZ;
#pragma unroll
  for (int r = 0; r < 16; ++r) {
    int c = r * 4 + ty;
    tile[c][tx] = xp[c * HWSZ + hwT + tx];
  }
  __syncthreads();
  float* xo = xt + ((size_t)b * HWSZ + hwT) * 64;
#pragma unroll
  for (int r = 0; r < 16; ++r) {
    int hwl = r * 4 + ty;
    xo[hwl * 64 + tx] = tile[tx][hwl];
  }
}

// ---- offset conv: 3x3, 64->18 ch, fp32, thread per pixel ----
__global__ void koffc(const float* __restrict__ xt, const float* __restrict__ offr,
                      const float* __restrict__ offb, float* __restrict__ offs) {
  int pix = blockIdx.x * 256 + threadIdx.x;
  int b = pix >> 14, hw = pix & 16383;
  int h = hw >> 7, w = hw & 127;
  float acc[18];
#pragma unroll
  for (int oc = 0; oc < 18; ++oc) acc[oc] = offb[oc];
#pragma unroll
  for (int k2 = 0; k2 < 9; ++k2) {
    int y = h - 1 + k2 / 3, x = w - 1 + k2 % 3;
    if ((unsigned)y < 128u && (unsigned)x < 128u) {
      const float* px = xt + (((b << 7) + y << 7) + x) * 64;
      const float* wr = offr + k2 * 64 * 18;
      for (int c = 0; c < 64; c += 4) {
        f32x4 xv = *(const f32x4*)(px + c);
#pragma unroll
        for (int j = 0; j < 4; ++j)
#pragma unroll
          for (int oc = 0; oc < 18; ++oc)
            acc[oc] = fmaf(wr[(c + j) * 18 + oc], xv[j], acc[oc]);
      }
    }
  }
  float* op = offs + (size_t)pix * 18;
#pragma unroll
  for (int oc = 0; oc < 18; ++oc) op[oc] = acc[oc];
}

// ---- deformable conv: dwordx4 corner-packed gathers + DPP reduce + MFMA ----
// block: 256 thr = 4 waves; tile = 64 o x 32 pixels; K = 576 (k2*64+c)
// LDS: 36864 B -> 4 blocks/CU
__global__ __launch_bounds__(256, 4) void kdeform(
    const float* __restrict__ xt, const float* __restrict__ offs,
    const u16* __restrict__ Wb, const float* __restrict__ db,
    float* __restrict__ y, float* __restrict__ stats) {
  __shared__ u16 S[32 * 576];          // XOR-swizzled: u16idx ^= (row&7)<<3
  int tid = threadIdx.x;
  int lane = tid & 63, wid = tid >> 6;
  int base = blockIdx.x * 32;
  int b = base >> 14;

  // sampling lane decomposition: corner = lane&3 (00,01,10,11 = y0x0,y0x1,y1x0,y1x1)
  int corner = lane & 3, c4 = lane >> 2;
  int gxsel = lane & 1, gysel = (lane >> 1) & 1;
  int lanebyte = c4 << 4;
  int shamt = gxsel << 4;              // 0 or 16: which half of packed weight

  // meta lanes: lane t<9 computes tap t
  int t = lane;
  int ky = t / 3, kx = t % 3;

  auto meta = [&](int pix, f32x2 dc, int& MO, int& WA, int& WB) {
    int hw = pix & 16383;
    int h = hw >> 7, w = hw & 127;
    float sy = (float)(h - 1 + ky) + dc.x;
    float sx = (float)(w - 1 + kx) + dc.y;
    float fy = floorf(sy), fx = floorf(sx);
    int y0 = (int)fy, x0 = (int)fx;
    float wy1 = sy - fy, wx1 = sx - fx;
    float ay0 = ((unsigned)y0 < 128u) ? 1.f - wy1 : 0.f;
    float ay1 = ((unsigned)(y0 + 1) < 128u) ? wy1 : 0.f;
    float ax0 = ((unsigned)x0 < 128u) ? 1.f - wx1 : 0.f;
    float ax1 = ((unsigned)(x0 + 1) < 128u) ? wx1 : 0.f;
    int y0c = min(max(y0, 0), 127), x0c = min(max(x0, 0), 127);
    int dys = min(max(y0 + 1, 0), 127) - y0c;
    int dxs = min(max(x0 + 1, 0), 127) - x0c;
    MO = ((b << 14) + y0c * 128 + x0c) | (dxs << 24) | (dys << 25);
    WA = __builtin_bit_cast(int, __floats2half2_rn(ay0 * ax0, ay0 * ax1));
    WB = __builtin_bit_cast(int, __floats2half2_rn(ay1 * ax0, ay1 * ax1));
  };
  auto bcast = [&](int MO, int WA, int WB, int (&smo)[9], int (&swA)[9], int (&swB)[9]) {
#pragma unroll
    for (int k = 0; k < 9; ++k) {
      smo[k] = __builtin_amdgcn_readlane(MO, k);
      swA[k] = __builtin_amdgcn_readlane(WA, k);
      swB[k] = __builtin_amdgcn_readlane(WB, k);
    }
  };
  auto issue = [&](const int (&smo)[9], f32x4 (&vv)[9]) {
#pragma unroll
    for (int k = 0; k < 9; ++k) {
      int mk = smo[k];
      int sdx = (mk >> 24) & 1;
      int sdy = ((mk >> 25) & 1) << 7;
      int po = (mk & 0xFFFFFF) + (gxsel ? sdx : 0) + (gysel ? sdy : 0);
      vv[k] = *(const f32x4*)((const char*)xt + ((size_t)(unsigned)po << 8) + lanebyte);
    }
  };
  auto reduce = [&](const int (&swA)[9], const int (&swB)[9], const f32x4 (&vv)[9], int p) {
#pragma unroll
    for (int k = 0; k < 9; ++k) {
      int hsel = gysel ? swB[k] : swA[k];
      __half hh = __builtin_bit_cast(__half, (u16)(hsel >> shamt));
      float w = __half2float(hh);
      float r0 = vv[k][0] * w, r1 = vv[k][1] * w, r2 = vv[k][2] * w, r3 = vv[k][3] * w;
      r0 = dpp_add_x2(dpp_add_x1(r0));
      r1 = dpp_add_x2(dpp_add_x1(r1));
      r2 = dpp_add_x2(dpp_add_x1(r2));
      r3 = dpp_add_x2(dpp_add_x1(r3));
      if (corner == 0) {
        ushort4v pk;
        pk.x = __builtin_bit_cast(u16, __float2bfloat16(r0));
        pk.y = __builtin_bit_cast(u16, __float2bfloat16(r1));
        pk.z = __builtin_bit_cast(u16, __float2bfloat16(r2));
        pk.w = __builtin_bit_cast(u16, __float2bfloat16(r3));
        int idx = (p * 576 + k * 64 + (c4 << 2)) ^ ((p & 7) << 3);
        *(ushort4v*)&S[idx] = pk;
      }
    }
  };

  // ---- software-pipelined sampling: 8 pixels per wave ----
  int p0 = wid * 8;
  f32x2 dcur = {0.f, 0.f}, dnext = {0.f, 0.f};
  if (t < 9) {
    dcur = *(const f32x2*)(offs + (size_t)(base + p0) * 18 + 2 * t);
    dnext = *(const f32x2*)(offs + (size_t)(base + p0 + 1) * 18 + 2 * t);
  }
  f32x4 vA[9], vB[9];
  int smoA[9], swAA[9], swBA[9], smoB[9], swAB[9], swBB[9];
  {
    int MO, WA, WB;
    meta(base + p0, dcur, MO, WA, WB);
    bcast(MO, WA, WB, smoA, swAA, swBA);
    issue(smoA, vA);
  }
  auto body = [&](int i, f32x4 (&vX)[9], int (&smoX)[9], int (&swAX)[9], int (&swBX)[9],
                  f32x4 (&vY)[9], int (&smoY)[9], int (&swAY)[9], int (&swBY)[9]) {
    int p = p0 + i;
    f32x2 dpre = {0.f, 0.f};
    if (i < 6 && t < 9)
      dpre = *(const f32x2*)(offs + (size_t)(base + p + 2) * 18 + 2 * t);
    if (i < 7) {
      int MO, WA, WB;
      meta(base + p + 1, dnext, MO, WA, WB);
      bcast(MO, WA, WB, smoY, swAY, swBY);
      issue(smoY, vY);
    }
    reduce(swAX, swBX, vX, p);
    dnext = dpre;
  };
  body(0, vA, smoA, swAA, swBA, vB, smoB, swAB, swBB);
  body(1, vB, smoB, swAB, swBB, vA, smoA, swAA, swBA);
  body(2, vA, smoA, swAA, swBA, vB, smoB, swAB, swBB);
  body(3, vB, smoB, swAB, swBB, vA, smoA, swAA, swBA);
  body(4, vA, smoA, swAA, swBA, vB, smoB, swAB, swBB);
  body(5, vB, smoB, swAB, swBB, vA, smoA, swAA, swBA);
  body(6, vA, smoA, swAA, swBA, vB, smoB, swAB, swBB);
  body(7, vB, smoB, swAB, swBB, vA, smoA, swAA, swBA);

  // A fragments: W rows for this wave's 16 output channels, K=576 in 18 steps
  bf16x8 af[18];
  const u16* wrow = Wb + (wid * 16 + (lane & 15)) * 576 + (lane >> 4) * 8;
#pragma unroll
  for (int kc = 0; kc < 18; ++kc)
    af[kc] = __builtin_bit_cast(bf16x8, *(const s16x8*)(wrow + kc * 32));

  __syncthreads();

  f32x4 zero = {0.f, 0.f, 0.f, 0.f};
  f32x4 acc[2] = {zero, zero};
#pragma unroll
  for (int kc = 0; kc < 18; ++kc) {
#pragma unroll
    for (int nf = 0; nf < 2; ++nf) {
      int row = nf * 16 + (lane & 15);
      int idx = (row * 576 + kc * 32 + (lane >> 4) * 8) ^ ((row & 7) << 3);
      bf16x8 bfr = __builtin_bit_cast(bf16x8, *(const s16x8*)&S[idx]);
      acc[nf] = __builtin_amdgcn_mfma_f32_16x16x32_bf16(af[kc], bfr, acc[nf], 0, 0, 0);
    }
  }

  // epilogue: write y (NCHW) + per-channel partial sums
  int obase = wid * 16 + (lane >> 4) * 4;
  float s1[4] = {0, 0, 0, 0}, s2[4] = {0, 0, 0, 0};
#pragma unroll
  for (int nf = 0; nf < 2; ++nf) {
    int pix = base + nf * 16 + (lane & 15);
    int hw = pix & 16383;
    float* yp = y + (size_t)b * (64 * HWSZ) + hw;
#pragma unroll
    for (int r = 0; r < 4; ++r) {
      int o = obase + r;
      float v = acc[nf][r] + db[o];
      yp[(size_t)o * HWSZ] = v;
      s1[r] += v;
      s2[r] += v * v;
    }
  }
#pragma unroll
  for (int m = 1; m < 16; m <<= 1) {
#pragma unroll
    for (int r = 0; r < 4; ++r) {
      s1[r] += __shfl_xor(s1[r], m, 64);
      s2[r] += __shfl_xor(s2[r], m, 64);
    }
  }
  if ((lane & 15) == 0) {
#pragma unroll
    for (int r = 0; r < 4; ++r) {
      atomicAdd(&stats[obase + r], s1[r]);
      atomicAdd(&stats[64 + obase + r], s2[r]);
    }
  }
}

// ---- BN finalize: scale/shift per channel ----
__global__ void kbn(const float* __restrict__ gamma, const float* __restrict__ beta,
                    float* __restrict__ stats) {
  int o = threadIdx.x;
  if (o < 64) {
    float m = stats[o] * (1.f / 131072.f);
    float v = stats[64 + o] * (1.f / 131072.f) - m * m;
    float sc = gamma[o] * rsqrtf(v + 1e-5f);
    stats[128 + o] = sc;
    stats[192 + o] = beta[o] - m * sc;
  }
}

// ---- in-place scale/shift + PReLU on y (= d_out) ----
__global__ void kfinal(float* __restrict__ y, const float* __restrict__ stats,
                       const float* __restrict__ pa) {
  float a = pa[0];
  int total = NPIX * 64 / 4;
  for (int i = blockIdx.x * blockDim.x + threadIdx.x; i < total;
       i += gridDim.x * blockDim.x) {
    int o = (i >> 12) & 63;
    f32x4 v = ((const f32x4*)y)[i];
    float sc = stats[128 + o], sh = stats[192 + o];
#pragma unroll
    for (int j = 0; j < 4; ++j) {
      float t = fmaf(v[j], sc, sh);
      v[j] = t >= 0.f ? t : a * t;
    }
    ((f32x4*)y)[i] = v;
  }
}

extern "C" void kernel_launch(void* const* d_in, const int* in_sizes, int n_in,
                              void* d_out, int out_size, void* d_ws, size_t ws_size,
                              hipStream_t stream) {
  const float* x  = (const float*)d_in[0];
  const float* ow = (const float*)d_in[1];
  const float* ob = (const float*)d_in[2];
  const float* dw = (const float*)d_in[3];
  const float* db = (const float*)d_in[4];
  const float* gm = (const float*)d_in[5];
  const float* bt = (const float*)d_in[6];
  const float* pa = (const float*)d_in[7];
  char* ws = (char*)d_ws;
  float* xt    = (float*)(ws + XT_OFF);
  float* offs  = (float*)(ws + OFFS_OFF);
  u16*   Wb    = (u16*)(ws + WB_OFF);
  float* offr  = (float*)(ws + OFFR_OFF);
  float* stats = (float*)(ws + STATS_OFF);
  float* y = (float*)d_out;   // d_out doubles as the pre-BN activation buffer

  kprep<<<185, 256, 0, stream>>>(dw, ow, Wb, offr, stats);
  ktrans<<<2048, 256, 0, stream>>>(x, xt);
  koffc<<<512, 256, 0, stream>>>(xt, offr, ob, offs);
  kdeform<<<4096, 256, 0, stream>>>(xt, offs, Wb, db, y, stats);
  kbn<<<1, 64, 0, stream>>>(gm, bt, stats);
  kfinal<<<2048, 256, 0, stream>>>(y, stats, pa);
}